// Round 6
// baseline (313.396 us; speedup 1.0000x reference)
//
#include <hip/hip_runtime.h>

// GPT2 grouped-query attention, bf16 MFMA pipeline, round 5.
// R3/R4 post-mortem: attn needs ~130 unified regs; both (256,4) and default
// (heuristic = 4 waves/EU = 128 regs) spilled the prefetch buffers to scratch
// (WRITE_SIZE 276/195 MB). R5: __launch_bounds__(256,2) grants 256 regs/wave.
// ws (u16 elems): q_att[8M] | k_att[8M] | v_t[8M] | Xb/ctx[8M] | Wcat[3M] | Wob[1M]

typedef __attribute__((ext_vector_type(8))) short short8;
typedef __attribute__((ext_vector_type(4))) float f32x4;
typedef unsigned int u32;
typedef unsigned short u16;

#define MFMA16(a, b, c) __builtin_amdgcn_mfma_f32_16x16x32_bf16((a), (b), (c), 0, 0, 0)

union S8 { short8 s; uint2 v[2]; u32 u[4]; };

__device__ __forceinline__ u32 f2bf1(float x) {
    union { float f; u32 u; } v; v.f = x;
    return (v.u + 0x7fffu + ((v.u >> 16) & 1u)) >> 16;   // RNE
}

__device__ __forceinline__ void gld16(u16* lds, const u16* g) {
    __builtin_amdgcn_global_load_lds(
        (const __attribute__((address_space(1))) unsigned int*)(g),
        (__attribute__((address_space(3))) unsigned int*)(lds),
        16, 0, 0);
}

// ---------------------------------------------------------------------------
// Kernel 0: fp32 -> bf16 convert.
// ---------------------------------------------------------------------------
__global__ __launch_bounds__(256) void convert(
    const float* __restrict__ X, const float* __restrict__ Wq,
    const float* __restrict__ Wk, const float* __restrict__ Wv,
    const float* __restrict__ Wo,
    u16* __restrict__ Xb, u16* __restrict__ Wcat, u16* __restrict__ Wob)
{
    const size_t M8 = 8388608, M1 = 1048576;
    size_t i = ((size_t)blockIdx.x * 256 + threadIdx.x) * 16;
    const float* src; u16* dst;
    if (i < M8)              { src = X  + i;                dst = Xb   + i; }
    else if (i < M8 + M1)    { src = Wq + (i - M8);         dst = Wcat + (i - M8); }
    else if (i < M8 + 2*M1)  { src = Wk + (i - M8 - M1);    dst = Wcat + (i - M8); }
    else if (i < M8 + 3*M1)  { src = Wv + (i - M8 - 2*M1);  dst = Wcat + (i - M8); }
    else                     { src = Wo + (i - M8 - 3*M1);  dst = Wob  + (i - M8 - 3*M1); }
#pragma unroll
    for (int j = 0; j < 2; ++j) {
        float4 a = ((const float4*)src)[2 * j];
        float4 b = ((const float4*)src)[2 * j + 1];
        uint4 o;
        o.x = f2bf1(a.x) | (f2bf1(a.y) << 16);
        o.y = f2bf1(a.z) | (f2bf1(a.w) << 16);
        o.z = f2bf1(b.x) | (f2bf1(b.y) << 16);
        o.w = f2bf1(b.z) | (f2bf1(b.w) << 16);
        ((uint4*)dst)[j] = o;
    }
}

// ---------------------------------------------------------------------------
// Kernel 1: fused QKV GEMM (m97 structure). C[8192][3072] = Xb @ Wcat^T.
// ---------------------------------------------------------------------------
__global__ __launch_bounds__(256) void qkv_gemm2(
    const u16* __restrict__ Xb, const u16* __restrict__ Wcat,
    const float* __restrict__ b0, const float* __restrict__ b1,
    const float* __restrict__ b2,
    u16* __restrict__ q_att, u16* __restrict__ k_att, u16* __restrict__ v_t)
{
    const int nb = blockIdx.x, mb = blockIdx.y;
    const int mat = nb >> 3;

    __shared__ __align__(16) u16 As[128 * 32];
    __shared__ __align__(16) u16 Bs[128 * 32];

    const int t = threadIdx.x, wave = t >> 6, lane = t & 63;
    const int l15 = lane & 15, quad = lane >> 4;
    const int wm = (wave >> 1) * 64, wn = (wave & 1) * 64;
    const int lrow = lane >> 2, lcb = (lane & 3) * 8;

    const u16* Ab = Xb   + (size_t)(mb * 128) * 1024;
    const u16* Bb = Wcat + (size_t)(nb * 128) * 1024;

    f32x4 acc[4][4] = {};

    for (int k0 = 0; k0 < 1024; k0 += 32) {
        __syncthreads();
#pragma unroll
        for (int j = 0; j < 2; ++j) {
            int chunk = wave * 2 + j;
            gld16(As + chunk * 512, Ab + (size_t)(chunk * 16 + lrow) * 1024 + k0 + lcb);
            gld16(Bs + chunk * 512, Bb + (size_t)(chunk * 16 + lrow) * 1024 + k0 + lcb);
        }
        __syncthreads();

        short8 af[4], bf[4];
#pragma unroll
        for (int mt = 0; mt < 4; ++mt)
            af[mt] = *(const short8*)(As + (wm + mt * 16 + l15) * 32 + quad * 8);
#pragma unroll
        for (int nt = 0; nt < 4; ++nt)
            bf[nt] = *(const short8*)(Bs + (wn + nt * 16 + l15) * 32 + quad * 8);
#pragma unroll
        for (int mt = 0; mt < 4; ++mt)
#pragma unroll
            for (int nt = 0; nt < 4; ++nt)
                acc[mt][nt] = MFMA16(af[mt], bf[nt], acc[mt][nt]);
    }

    const float* bias = (mat == 0) ? b0 : (mat == 1) ? b1 : b2;
#pragma unroll
    for (int nt = 0; nt < 4; ++nt) {
        int colm = (nb & 7) * 128 + wn + nt * 16 + l15;   // feature = h*64+dh
        float bv = bias[colm];
        int h = colm >> 6, dh = colm & 63;
#pragma unroll
        for (int mt = 0; mt < 4; ++mt) {
            int row0 = mb * 128 + wm + mt * 16 + quad * 4;
            int b = row0 >> 11, s0 = row0 & 2047;
            int bh = b * 16 + h, g0 = s0 >> 1;
            if (mat == 2) {
                float v0 = acc[mt][nt][0] + bv, v1 = acc[mt][nt][1] + bv;
                float v2 = acc[mt][nt][2] + bv, v3 = acc[mt][nt][3] + bv;
                u32 w0 = f2bf1(v0) | (f2bf1(v2) << 16);
                u32 w1 = f2bf1(v1) | (f2bf1(v3) << 16);
                *(u32*)(v_t + ((size_t)(bh * 128 + dh) * 1024 + g0)) = w0;
                *(u32*)(v_t + ((size_t)(bh * 128 + dh + 64) * 1024 + g0)) = w1;
            } else {
#pragma unroll
                for (int r = 0; r < 4; ++r) {
                    int s = s0 + r;
                    int g = s >> 1, dp = (s & 1) * 64 + dh;
                    float v = acc[mt][nt][r] + bv;
                    if (mat == 0)
                        q_att[((size_t)bh * 1024 + g) * 128 + dp] = (u16)f2bf1(v * 0.125f);
                    else
                        k_att[((size_t)bh * 1024 + g) * 128 + dp] = (u16)f2bf1(v);
                }
            }
        }
    }
}

// ---------------------------------------------------------------------------
// Kernel 2: flash attention, transposed-S + reg-dbuf staging. grid (16,64).
// Vs swizzled: per 32-key block, pos(k) = ((k>>2)&3)*8 + ((k>>4)&1)*4 + (k&3)
// so PV A-frag = one b128 and P B-frag = concat of two S^T D-frags.
// __launch_bounds__(256,2): needs ~130 unified regs; 4-waves/EU budget (128)
// spills (R3: 56 VGPR/276MB scratch, R4 default: 96 VGPR/195MB scratch).
// ---------------------------------------------------------------------------
__global__ __launch_bounds__(256, 2) void attn3(
    const u16* __restrict__ q_att, const u16* __restrict__ k_att,
    const u16* __restrict__ v_t, u16* __restrict__ ctx)
{
    const int bh = blockIdx.y, qb = blockIdx.x;
    const u16* Q = q_att + (size_t)bh * 131072;
    const u16* K = k_att + (size_t)bh * 131072;
    const u16* V = v_t  + (size_t)bh * 131072;     // [d'=128][g=1024]

    __shared__ __align__(16) u16 Ks[64 * 136];     // [key][d'], stride 136
    __shared__ __align__(16) u16 Vs[128 * 72];     // [d'][key-swizzled], stride 72

    const int t = threadIdx.x, wave = t >> 6, lane = t & 63;
    const int l15 = lane & 15, quad = lane >> 4;
    const int q_row = qb * 64 + wave * 16 + l15;

    // staging geometry (per thread)
    const int kR = t >> 4 /* +16i */, kC = (t & 15) * 8;          // K: row, col
    const int vD = t >> 3 /* +32i */, vc8 = t & 7;                // V: d', col-chunk
    const int vBlk = (vc8 >> 2) * 32, vcc = vc8 & 3;
    const int vHi = (vcc >> 1) * 4, vM0 = (vcc * 2) & 3;          // swizzle params
    const int vOff0 = vBlk + vM0 * 8 + vHi, vOff1 = vBlk + (vM0 + 1) * 8 + vHi;

    // Q^T B-frags: n=l15=q, k=dh=quad*8+j over 4 blocks of 32
    short8 bq[4];
#pragma unroll
    for (int kb = 0; kb < 4; ++kb)
        bq[kb] = *(const short8*)(Q + (size_t)q_row * 128 + kb * 32 + quad * 8);

    // prefetch tile 0 into regs
    uint4 kr[4], vr[4];
#pragma unroll
    for (int i = 0; i < 4; ++i) {
        kr[i] = *(const uint4*)(K + (size_t)(16 * i + kR) * 128 + kC);
        vr[i] = *(const uint4*)(V + (size_t)(32 * i + vD) * 1024 + vc8 * 8);
    }

    f32x4 accO[8] = {};
    float m_i = -1e30f, l_i = 0.0f;

    for (int kt = 0; kt < 16; ++kt) {
        __syncthreads();                            // prev tile's LDS reads done
        // write current regs -> LDS
#pragma unroll
        for (int i = 0; i < 4; ++i) {
            *(uint4*)(Ks + (16 * i + kR) * 136 + kC) = kr[i];
            uint2 lo, hi;
            lo.x = vr[i].x; lo.y = vr[i].y; hi.x = vr[i].z; hi.y = vr[i].w;
            *(uint2*)(Vs + (32 * i + vD) * 72 + vOff0) = lo;
            *(uint2*)(Vs + (32 * i + vD) * 72 + vOff1) = hi;
        }
        __syncthreads();
        // prefetch next tile (latency hidden behind compute below)
        if (kt < 15) {
            const u16* Kn = K + (size_t)(kt + 1) * 8192;
            const u16* Vn = V + (size_t)(kt + 1) * 64;
#pragma unroll
            for (int i = 0; i < 4; ++i) {
                kr[i] = *(const uint4*)(Kn + (size_t)(16 * i + kR) * 128 + kC);
                vr[i] = *(const uint4*)(Vn + (size_t)(32 * i + vD) * 1024 + vc8 * 8);
            }
        }

        // S^T: accS[kf] = K[16 keys] x Q^T
        f32x4 accS[4] = {};
#pragma unroll
        for (int kf = 0; kf < 4; ++kf)
#pragma unroll
            for (int kb = 0; kb < 4; ++kb) {
                short8 ak = *(const short8*)(Ks + (kf * 16 + l15) * 136 + kb * 32 + quad * 8);
                accS[kf] = MFMA16(ak, bq[kb], accS[kf]);
            }

        // per-lane softmax over 64 keys (16 regs + cross-quad shuffles)
        float mloc = -1e30f;
#pragma unroll
        for (int kf = 0; kf < 4; ++kf)
            mloc = fmaxf(mloc, fmaxf(fmaxf(accS[kf][0], accS[kf][1]),
                                     fmaxf(accS[kf][2], accS[kf][3])));
        mloc = fmaxf(mloc, __shfl_xor(mloc, 16));
        mloc = fmaxf(mloc, __shfl_xor(mloc, 32));
        float mn = fmaxf(m_i, mloc);
        float alpha = __expf(m_i - mn);
        m_i = mn;

        float lsum = 0.0f;
        u32 pb[8];
#pragma unroll
        for (int kf = 0; kf < 4; ++kf) {
            float p0 = __expf(accS[kf][0] - mn);
            float p1 = __expf(accS[kf][1] - mn);
            float p2 = __expf(accS[kf][2] - mn);
            float p3 = __expf(accS[kf][3] - mn);
            lsum += (p0 + p1) + (p2 + p3);
            pb[kf * 2]     = f2bf1(p0) | (f2bf1(p1) << 16);
            pb[kf * 2 + 1] = f2bf1(p2) | (f2bf1(p3) << 16);
        }
        lsum += __shfl_xor(lsum, 16);
        lsum += __shfl_xor(lsum, 32);
        l_i = l_i * alpha + lsum;

#pragma unroll
        for (int f = 0; f < 8; ++f) {
            accO[f][0] *= alpha; accO[f][1] *= alpha;
            accO[f][2] *= alpha; accO[f][3] *= alpha;
        }

        // PV: O^T += V^T @ P^T (swizzled Vs -> single b128 A-frags)
        S8 bp0, bp1;
        bp0.u[0] = pb[0]; bp0.u[1] = pb[1]; bp0.u[2] = pb[2]; bp0.u[3] = pb[3];
        bp1.u[0] = pb[4]; bp1.u[1] = pb[5]; bp1.u[2] = pb[6]; bp1.u[3] = pb[7];
#pragma unroll
        for (int df = 0; df < 8; ++df) {
            const u16* vrow = Vs + (df * 16 + l15) * 72 + quad * 8;
            short8 av0 = *(const short8*)(vrow);
            short8 av1 = *(const short8*)(vrow + 32);
            accO[df] = MFMA16(av0, bp0.s, accO[df]);
            accO[df] = MFMA16(av1, bp1.s, accO[df]);
        }
    }

    // epilogue: O^T/l -> ctx[b][sp=2q+(h>>3)][(h&7)*128 + d'], 8B stores
    const int h = bh & 15, b = bh >> 4;
    float inv = 1.0f / l_i;
    size_t base = ((size_t)(b * 2048 + 2 * q_row + (h >> 3))) * 1024 + (h & 7) * 128;
#pragma unroll
    for (int df = 0; df < 8; ++df) {
        int dp = df * 16 + quad * 4;
        uint2 w;
        w.x = f2bf1(accO[df][0] * inv) | (f2bf1(accO[df][1] * inv) << 16);
        w.y = f2bf1(accO[df][2] * inv) | (f2bf1(accO[df][3] * inv) << 16);
        *(uint2*)(ctx + base + dp) = w;
    }
}

// ---------------------------------------------------------------------------
// Kernel 3: out = ctx(bf16) @ Wob^T + bo -> fp32. 64x128 tile, grid (8,128).
// ---------------------------------------------------------------------------
__global__ __launch_bounds__(256) void out_gemm3(
    const u16* __restrict__ ctx, const u16* __restrict__ Wob,
    const float* __restrict__ bo, float* __restrict__ out)
{
    const int nb = blockIdx.x, mb = blockIdx.y;
    __shared__ __align__(16) u16 As[64 * 32];
    __shared__ __align__(16) u16 Bs[128 * 32];
    const int t = threadIdx.x, wave = t >> 6, lane = t & 63;
    const int l15 = lane & 15, quad = lane >> 4;
    const int wm = (wave >> 1) * 32, wn = (wave & 1) * 64;
    const int lrow = lane >> 2, lcb = (lane & 3) * 8;

    const u16* Ab = ctx + (size_t)(mb * 64) * 1024;
    const u16* Bb = Wob + (size_t)(nb * 128) * 1024;

    f32x4 acc[2][4] = {};

    for (int k0 = 0; k0 < 1024; k0 += 32) {
        __syncthreads();
#pragma unroll
        for (int j = 0; j < 3; ++j) {
            int c = wave * 3 + j;                    // 12 chunks: 4 A + 8 B
            if (c < 4)
                gld16(As + c * 512, Ab + (size_t)(c * 16 + lrow) * 1024 + k0 + lcb);
            else
                gld16(Bs + (c - 4) * 512, Bb + (size_t)((c - 4) * 16 + lrow) * 1024 + k0 + lcb);
        }
        __syncthreads();

        short8 af[2], bf[4];
#pragma unroll
        for (int mt = 0; mt < 2; ++mt)
            af[mt] = *(const short8*)(As + (wm + mt * 16 + l15) * 32 + quad * 8);
#pragma unroll
        for (int nt = 0; nt < 4; ++nt)
            bf[nt] = *(const short8*)(Bs + (wn + nt * 16 + l15) * 32 + quad * 8);
#pragma unroll
        for (int mt = 0; mt < 2; ++mt)
#pragma unroll
            for (int nt = 0; nt < 4; ++nt)
                acc[mt][nt] = MFMA16(af[mt], bf[nt], acc[mt][nt]);
    }

#pragma unroll
    for (int nt = 0; nt < 4; ++nt) {
        int col = nb * 128 + wn + nt * 16 + l15;
        float bv = bo[col];
#pragma unroll
        for (int mt = 0; mt < 2; ++mt)
#pragma unroll
            for (int r = 0; r < 4; ++r) {
                int row = mb * 64 + wm + mt * 16 + quad * 4 + r;
                out[(size_t)row * 1024 + col] = acc[mt][nt][r] + bv;
            }
    }
}

// ---------------------------------------------------------------------------
extern "C" void kernel_launch(void* const* d_in, const int* in_sizes, int n_in,
                              void* d_out, int out_size, void* d_ws, size_t ws_size,
                              hipStream_t stream)
{
    const float* X  = (const float*)d_in[0];
    const float* Wq = (const float*)d_in[1];
    const float* bq = (const float*)d_in[2];
    const float* Wk = (const float*)d_in[3];
    const float* bk = (const float*)d_in[4];
    const float* Wv = (const float*)d_in[5];
    const float* bv = (const float*)d_in[6];
    const float* Wo = (const float*)d_in[7];
    const float* bo = (const float*)d_in[8];

    const size_t M8 = 8388608;
    u16* q_att = (u16*)d_ws;
    u16* k_att = q_att + M8;
    u16* v_t   = k_att + M8;
    u16* Xb    = v_t   + M8;            // Xb dead after qkv -> ctx aliases it
    u16* ctx   = Xb;
    u16* Wcat  = Xb + M8;
    u16* Wob   = Wcat + 3 * 1048576;

    convert<<<dim3(3072), 256, 0, stream>>>(X, Wq, Wk, Wv, Wo, Xb, Wcat, Wob);
    qkv_gemm2<<<dim3(24, 64), 256, 0, stream>>>(Xb, Wcat, bq, bk, bv,
                                                q_att, k_att, v_t);
    attn3<<<dim3(16, 64), 256, 0, stream>>>(q_att, k_att, v_t, ctx);
    out_gemm3<<<dim3(8, 128), 256, 0, stream>>>(ctx, Wob, bo, (float*)d_out);
}

// Round 7
// 272.765 us; speedup vs baseline: 1.1490x; 1.1490x over previous
//
#include <hip/hip_runtime.h>

// GPT2 grouped-query attention, bf16 MFMA pipeline, round 6.
// R3-R5 lesson: register-prefetch staging in attn always spills (allocator
// won't exceed ~128 unified regs regardless of launch_bounds). R6: stage via
// global_load_lds (zero staging VGPRs) with XOR-swizzled LDS layouts
// (swizzle folded into per-lane *source* addresses; LDS dest stays
// lane-contiguous) and the PV key-permutation baked into v_t's global layout.
// ws (u16 elems): q_att[8M] | k_att[8M] | v_t[8M] | Xb/ctx[8M] | Wcat[3M] | Wob[1M]

typedef __attribute__((ext_vector_type(8))) short short8;
typedef __attribute__((ext_vector_type(4))) float f32x4;
typedef unsigned int u32;
typedef unsigned short u16;

#define MFMA16(a, b, c) __builtin_amdgcn_mfma_f32_16x16x32_bf16((a), (b), (c), 0, 0, 0)

union S8 { short8 s; uint2 v[2]; u32 u[4]; };

__device__ __forceinline__ u32 f2bf1(float x) {
    union { float f; u32 u; } v; v.f = x;
    return (v.u + 0x7fffu + ((v.u >> 16) & 1u)) >> 16;   // RNE
}

__device__ __forceinline__ void gld16(u16* lds, const u16* g) {
    __builtin_amdgcn_global_load_lds(
        (const __attribute__((address_space(1))) unsigned int*)(g),
        (__attribute__((address_space(3))) unsigned int*)(lds),
        16, 0, 0);
}

// ---------------------------------------------------------------------------
// Kernel 0: fp32 -> bf16 convert.
// ---------------------------------------------------------------------------
__global__ __launch_bounds__(256) void convert(
    const float* __restrict__ X, const float* __restrict__ Wq,
    const float* __restrict__ Wk, const float* __restrict__ Wv,
    const float* __restrict__ Wo,
    u16* __restrict__ Xb, u16* __restrict__ Wcat, u16* __restrict__ Wob)
{
    const size_t M8 = 8388608, M1 = 1048576;
    size_t i = ((size_t)blockIdx.x * 256 + threadIdx.x) * 16;
    const float* src; u16* dst;
    if (i < M8)              { src = X  + i;                dst = Xb   + i; }
    else if (i < M8 + M1)    { src = Wq + (i - M8);         dst = Wcat + (i - M8); }
    else if (i < M8 + 2*M1)  { src = Wk + (i - M8 - M1);    dst = Wcat + (i - M8); }
    else if (i < M8 + 3*M1)  { src = Wv + (i - M8 - 2*M1);  dst = Wcat + (i - M8); }
    else                     { src = Wo + (i - M8 - 3*M1);  dst = Wob  + (i - M8 - 3*M1); }
#pragma unroll
    for (int j = 0; j < 2; ++j) {
        float4 a = ((const float4*)src)[2 * j];
        float4 b = ((const float4*)src)[2 * j + 1];
        uint4 o;
        o.x = f2bf1(a.x) | (f2bf1(a.y) << 16);
        o.y = f2bf1(a.z) | (f2bf1(a.w) << 16);
        o.z = f2bf1(b.x) | (f2bf1(b.y) << 16);
        o.w = f2bf1(b.z) | (f2bf1(b.w) << 16);
        ((uint4*)dst)[j] = o;
    }
}

// ---------------------------------------------------------------------------
// Kernel 1: fused QKV GEMM (m97 structure). C[8192][3072] = Xb @ Wcat^T.
// v_t written with the PV sigma key-permutation baked in:
// pos64(j) = (j&32) + ((j>>2)&3)*8 + ((j>>4)&1)*4 + (j&3).
// ---------------------------------------------------------------------------
__global__ __launch_bounds__(256) void qkv_gemm2(
    const u16* __restrict__ Xb, const u16* __restrict__ Wcat,
    const float* __restrict__ b0, const float* __restrict__ b1,
    const float* __restrict__ b2,
    u16* __restrict__ q_att, u16* __restrict__ k_att, u16* __restrict__ v_t)
{
    const int nb = blockIdx.x, mb = blockIdx.y;
    const int mat = nb >> 3;

    __shared__ __align__(16) u16 As[128 * 32];
    __shared__ __align__(16) u16 Bs[128 * 32];

    const int t = threadIdx.x, wave = t >> 6, lane = t & 63;
    const int l15 = lane & 15, quad = lane >> 4;
    const int wm = (wave >> 1) * 64, wn = (wave & 1) * 64;
    const int lrow = lane >> 2, lcb = (lane & 3) * 8;

    const u16* Ab = Xb   + (size_t)(mb * 128) * 1024;
    const u16* Bb = Wcat + (size_t)(nb * 128) * 1024;

    f32x4 acc[4][4] = {};

    for (int k0 = 0; k0 < 1024; k0 += 32) {
        __syncthreads();
#pragma unroll
        for (int j = 0; j < 2; ++j) {
            int chunk = wave * 2 + j;
            gld16(As + chunk * 512, Ab + (size_t)(chunk * 16 + lrow) * 1024 + k0 + lcb);
            gld16(Bs + chunk * 512, Bb + (size_t)(chunk * 16 + lrow) * 1024 + k0 + lcb);
        }
        __syncthreads();

        short8 af[4], bf[4];
#pragma unroll
        for (int mt = 0; mt < 4; ++mt)
            af[mt] = *(const short8*)(As + (wm + mt * 16 + l15) * 32 + quad * 8);
#pragma unroll
        for (int nt = 0; nt < 4; ++nt)
            bf[nt] = *(const short8*)(Bs + (wn + nt * 16 + l15) * 32 + quad * 8);
#pragma unroll
        for (int mt = 0; mt < 4; ++mt)
#pragma unroll
            for (int nt = 0; nt < 4; ++nt)
                acc[mt][nt] = MFMA16(af[mt], bf[nt], acc[mt][nt]);
    }

    const float* bias = (mat == 0) ? b0 : (mat == 1) ? b1 : b2;
#pragma unroll
    for (int nt = 0; nt < 4; ++nt) {
        int colm = (nb & 7) * 128 + wn + nt * 16 + l15;   // feature = h*64+dh
        float bv = bias[colm];
        int h = colm >> 6, dh = colm & 63;
#pragma unroll
        for (int mt = 0; mt < 4; ++mt) {
            int row0 = mb * 128 + wm + mt * 16 + quad * 4;
            int b = row0 >> 11, s0 = row0 & 2047;
            int bh = b * 16 + h, g0 = s0 >> 1;                // even
            if (mat == 2) {
                // keys (g0,g0+1): dp=dh from rows r0,r2; dp=dh+64 from r1,r3
                float v0 = acc[mt][nt][0] + bv, v1 = acc[mt][nt][1] + bv;
                float v2 = acc[mt][nt][2] + bv, v3 = acc[mt][nt][3] + bv;
                u32 w0 = f2bf1(v0) | (f2bf1(v2) << 16);
                u32 w1 = f2bf1(v1) | (f2bf1(v3) << 16);
                int j6 = g0 & 63;
                int gp = (g0 & ~63) + (j6 & 32) + ((j6 >> 2) & 3) * 8
                       + ((j6 >> 4) & 1) * 4 + (j6 & 3);      // sigma-permuted
                *(u32*)(v_t + ((size_t)(bh * 128 + dh) * 1024 + gp)) = w0;
                *(u32*)(v_t + ((size_t)(bh * 128 + dh + 64) * 1024 + gp)) = w1;
            } else {
#pragma unroll
                for (int r = 0; r < 4; ++r) {
                    int s = s0 + r;
                    int g = s >> 1, dp = (s & 1) * 64 + dh;
                    float v = acc[mt][nt][r] + bv;
                    if (mat == 0)
                        q_att[((size_t)bh * 1024 + g) * 128 + dp] = (u16)f2bf1(v * 0.125f);
                    else
                        k_att[((size_t)bh * 1024 + g) * 128 + dp] = (u16)f2bf1(v);
                }
            }
        }
    }
}

// ---------------------------------------------------------------------------
// Kernel 2: flash attention, transposed-S, global_load_lds staging with
// XOR-swizzled LDS. grid (16,64), 256 thr.
//  Ks[64][128]: phys 16B-chunk = logical ^ (row&15)  -> b128 reads 8 words/bank
//  Vs[128][64]: phys 16B-chunk = logical ^ (row&7)   -> b128 reads 8 words/bank
// Swizzle lives in the fill's per-lane SOURCE address (LDS dest lane-linear).
// ---------------------------------------------------------------------------
__global__ __launch_bounds__(256) void attn4(
    const u16* __restrict__ q_att, const u16* __restrict__ k_att,
    const u16* __restrict__ v_t, u16* __restrict__ ctx)
{
    const int bh = blockIdx.y, qb = blockIdx.x;
    const u16* Q = q_att + (size_t)bh * 131072;
    const u16* K = k_att + (size_t)bh * 131072;
    const u16* V = v_t  + (size_t)bh * 131072;     // [d'=128][g-sigma-permuted]

    __shared__ __align__(16) u16 Ks[64 * 128];     // 16KB
    __shared__ __align__(16) u16 Vs[128 * 64];     // 16KB

    const int t = threadIdx.x, wave = t >> 6, lane = t & 63;
    const int l15 = lane & 15, quad = lane >> 4;
    const int q_row = qb * 64 + wave * 16 + l15;

    // staging source offsets (u16 units), 4 K-chunks + 4 V-chunks per wave
    int offK[4], offV[4];
#pragma unroll
    for (int j = 0; j < 4; ++j) {
        int ck = wave * 4 + j;
        int rowK = ck * 4 + (lane >> 4);                       // 0..63
        offK[j] = rowK * 128 + (((lane & 15) ^ (rowK & 15)) * 8);
        int rowV = ck * 8 + (lane >> 3);                       // d' 0..127
        offV[j] = rowV * 1024 + (((lane & 7) ^ ((lane >> 3) & 7)) * 8);
    }

    // Q^T B-frags: n=l15=q, k=dh=quad*8+j over 4 blocks of 32
    short8 bq[4];
#pragma unroll
    for (int kb = 0; kb < 4; ++kb)
        bq[kb] = *(const short8*)(Q + (size_t)q_row * 128 + kb * 32 + quad * 8);

    f32x4 accO[8] = {};
    float m_i = -1e30f, l_i = 0.0f;

    for (int kt = 0; kt < 16; ++kt) {
        const u16* Kt = K + (size_t)kt * 8192;
        const u16* Vt = V + (size_t)kt * 64;
        __syncthreads();                            // prev tile's LDS reads done
#pragma unroll
        for (int j = 0; j < 4; ++j) {
            gld16(Ks + (wave * 4 + j) * 512, Kt + offK[j]);
            gld16(Vs + (wave * 4 + j) * 512, Vt + offV[j]);
        }
        __syncthreads();                            // drains vmcnt incl. lds-DMA

        // S^T: accS[kf] = K[16 keys] x Q^T  (Ks xor-swizzled reads)
        f32x4 accS[4] = {};
#pragma unroll
        for (int kf = 0; kf < 4; ++kf)
#pragma unroll
            for (int kb = 0; kb < 4; ++kb) {
                short8 ak = *(const short8*)(Ks + (kf * 16 + l15) * 128
                                             + (((kb * 4 + quad) ^ l15) * 8));
                accS[kf] = MFMA16(ak, bq[kb], accS[kf]);
            }

        // per-lane softmax over 64 keys
        float mloc = -1e30f;
#pragma unroll
        for (int kf = 0; kf < 4; ++kf)
            mloc = fmaxf(mloc, fmaxf(fmaxf(accS[kf][0], accS[kf][1]),
                                     fmaxf(accS[kf][2], accS[kf][3])));
        mloc = fmaxf(mloc, __shfl_xor(mloc, 16));
        mloc = fmaxf(mloc, __shfl_xor(mloc, 32));
        float mn = fmaxf(m_i, mloc);
        float alpha = __expf(m_i - mn);
        m_i = mn;

        float lsum = 0.0f;
        u32 pb[8];
#pragma unroll
        for (int kf = 0; kf < 4; ++kf) {
            float p0 = __expf(accS[kf][0] - mn);
            float p1 = __expf(accS[kf][1] - mn);
            float p2 = __expf(accS[kf][2] - mn);
            float p3 = __expf(accS[kf][3] - mn);
            lsum += (p0 + p1) + (p2 + p3);
            pb[kf * 2]     = f2bf1(p0) | (f2bf1(p1) << 16);
            pb[kf * 2 + 1] = f2bf1(p2) | (f2bf1(p3) << 16);
        }
        lsum += __shfl_xor(lsum, 16);
        lsum += __shfl_xor(lsum, 32);
        l_i = l_i * alpha + lsum;

#pragma unroll
        for (int f = 0; f < 8; ++f) {
            accO[f][0] *= alpha; accO[f][1] *= alpha;
            accO[f][2] *= alpha; accO[f][3] *= alpha;
        }

        // PV: O^T += V^T @ P^T (sigma baked into v_t; Vs xor-swizzled reads)
        S8 bp0, bp1;
        bp0.u[0] = pb[0]; bp0.u[1] = pb[1]; bp0.u[2] = pb[2]; bp0.u[3] = pb[3];
        bp1.u[0] = pb[4]; bp1.u[1] = pb[5]; bp1.u[2] = pb[6]; bp1.u[3] = pb[7];
        const int l7 = l15 & 7;
#pragma unroll
        for (int df = 0; df < 8; ++df) {
            const u16* vrow = Vs + (df * 16 + l15) * 64;
            short8 av0 = *(const short8*)(vrow + ((quad ^ l7) * 8));
            short8 av1 = *(const short8*)(vrow + (((quad + 4) ^ l7) * 8));
            accO[df] = MFMA16(av0, bp0.s, accO[df]);
            accO[df] = MFMA16(av1, bp1.s, accO[df]);
        }
    }

    // epilogue: O^T/l -> ctx[b][sp=2q+(h>>3)][(h&7)*128 + d'], 8B stores
    const int h = bh & 15, b = bh >> 4;
    float inv = 1.0f / l_i;
    size_t base = ((size_t)(b * 2048 + 2 * q_row + (h >> 3))) * 1024 + (h & 7) * 128;
#pragma unroll
    for (int df = 0; df < 8; ++df) {
        int dp = df * 16 + quad * 4;
        uint2 w;
        w.x = f2bf1(accO[df][0] * inv) | (f2bf1(accO[df][1] * inv) << 16);
        w.y = f2bf1(accO[df][2] * inv) | (f2bf1(accO[df][3] * inv) << 16);
        *(uint2*)(ctx + base + dp) = w;
    }
}

// ---------------------------------------------------------------------------
// Kernel 3: out = ctx(bf16) @ Wob^T + bo -> fp32. 64x128 tile, grid (8,128).
// ---------------------------------------------------------------------------
__global__ __launch_bounds__(256) void out_gemm3(
    const u16* __restrict__ ctx, const u16* __restrict__ Wob,
    const float* __restrict__ bo, float* __restrict__ out)
{
    const int nb = blockIdx.x, mb = blockIdx.y;
    __shared__ __align__(16) u16 As[64 * 32];
    __shared__ __align__(16) u16 Bs[128 * 32];
    const int t = threadIdx.x, wave = t >> 6, lane = t & 63;
    const int l15 = lane & 15, quad = lane >> 4;
    const int wm = (wave >> 1) * 32, wn = (wave & 1) * 64;
    const int lrow = lane >> 2, lcb = (lane & 3) * 8;

    const u16* Ab = ctx + (size_t)(mb * 64) * 1024;
    const u16* Bb = Wob + (size_t)(nb * 128) * 1024;

    f32x4 acc[2][4] = {};

    for (int k0 = 0; k0 < 1024; k0 += 32) {
        __syncthreads();
#pragma unroll
        for (int j = 0; j < 3; ++j) {
            int c = wave * 3 + j;                    // 12 chunks: 4 A + 8 B
            if (c < 4)
                gld16(As + c * 512, Ab + (size_t)(c * 16 + lrow) * 1024 + k0 + lcb);
            else
                gld16(Bs + (c - 4) * 512, Bb + (size_t)((c - 4) * 16 + lrow) * 1024 + k0 + lcb);
        }
        __syncthreads();

        short8 af[2], bf[4];
#pragma unroll
        for (int mt = 0; mt < 2; ++mt)
            af[mt] = *(const short8*)(As + (wm + mt * 16 + l15) * 32 + quad * 8);
#pragma unroll
        for (int nt = 0; nt < 4; ++nt)
            bf[nt] = *(const short8*)(Bs + (wn + nt * 16 + l15) * 32 + quad * 8);
#pragma unroll
        for (int mt = 0; mt < 2; ++mt)
#pragma unroll
            for (int nt = 0; nt < 4; ++nt)
                acc[mt][nt] = MFMA16(af[mt], bf[nt], acc[mt][nt]);
    }

#pragma unroll
    for (int nt = 0; nt < 4; ++nt) {
        int col = nb * 128 + wn + nt * 16 + l15;
        float bv = bo[col];
#pragma unroll
        for (int mt = 0; mt < 2; ++mt)
#pragma unroll
            for (int r = 0; r < 4; ++r) {
                int row = mb * 64 + wm + mt * 16 + quad * 4 + r;
                out[(size_t)row * 1024 + col] = acc[mt][nt][r] + bv;
            }
    }
}

// ---------------------------------------------------------------------------
extern "C" void kernel_launch(void* const* d_in, const int* in_sizes, int n_in,
                              void* d_out, int out_size, void* d_ws, size_t ws_size,
                              hipStream_t stream)
{
    const float* X  = (const float*)d_in[0];
    const float* Wq = (const float*)d_in[1];
    const float* bq = (const float*)d_in[2];
    const float* Wk = (const float*)d_in[3];
    const float* bk = (const float*)d_in[4];
    const float* Wv = (const float*)d_in[5];
    const float* bv = (const float*)d_in[6];
    const float* Wo = (const float*)d_in[7];
    const float* bo = (const float*)d_in[8];

    const size_t M8 = 8388608;
    u16* q_att = (u16*)d_ws;
    u16* k_att = q_att + M8;
    u16* v_t   = k_att + M8;
    u16* Xb    = v_t   + M8;            // Xb dead after qkv -> ctx aliases it
    u16* ctx   = Xb;
    u16* Wcat  = Xb + M8;
    u16* Wob   = Wcat + 3 * 1048576;

    convert<<<dim3(3072), 256, 0, stream>>>(X, Wq, Wk, Wv, Wo, Xb, Wcat, Wob);
    qkv_gemm2<<<dim3(24, 64), 256, 0, stream>>>(Xb, Wcat, bq, bk, bv,
                                                q_att, k_att, v_t);
    attn4<<<dim3(16, 64), 256, 0, stream>>>(q_att, k_att, v_t, ctx);
    out_gemm3<<<dim3(8, 128), 256, 0, stream>>>(ctx, Wob, bo, (float*)d_out);
}

// Round 8
// 269.978 us; speedup vs baseline: 1.1608x; 1.0103x over previous
//
#include <hip/hip_runtime.h>

// GPT2 grouped-query attention, bf16 MFMA pipeline, round 7.
// R7: (1) q/k stored with dp' = 2*dh + (s&1) feature permutation (QK dot is
// permutation-invariant when Q,K share it; attn reads both linearly) ->
// epilogue packs u32 stores like v_t. (2) out_gemm back to 128x128 m97 tile.
// ws (u16 elems): q_att[8M] | k_att[8M] | v_t[8M] | Xb/ctx[8M] | Wcat[3M] | Wob[1M]

typedef __attribute__((ext_vector_type(8))) short short8;
typedef __attribute__((ext_vector_type(4))) float f32x4;
typedef unsigned int u32;
typedef unsigned short u16;

#define MFMA16(a, b, c) __builtin_amdgcn_mfma_f32_16x16x32_bf16((a), (b), (c), 0, 0, 0)

union S8 { short8 s; uint2 v[2]; u32 u[4]; };

__device__ __forceinline__ u32 f2bf1(float x) {
    union { float f; u32 u; } v; v.f = x;
    return (v.u + 0x7fffu + ((v.u >> 16) & 1u)) >> 16;   // RNE
}

__device__ __forceinline__ void gld16(u16* lds, const u16* g) {
    __builtin_amdgcn_global_load_lds(
        (const __attribute__((address_space(1))) unsigned int*)(g),
        (__attribute__((address_space(3))) unsigned int*)(lds),
        16, 0, 0);
}

// ---------------------------------------------------------------------------
// Kernel 0: fp32 -> bf16 convert.
// ---------------------------------------------------------------------------
__global__ __launch_bounds__(256) void convert(
    const float* __restrict__ X, const float* __restrict__ Wq,
    const float* __restrict__ Wk, const float* __restrict__ Wv,
    const float* __restrict__ Wo,
    u16* __restrict__ Xb, u16* __restrict__ Wcat, u16* __restrict__ Wob)
{
    const size_t M8 = 8388608, M1 = 1048576;
    size_t i = ((size_t)blockIdx.x * 256 + threadIdx.x) * 16;
    const float* src; u16* dst;
    if (i < M8)              { src = X  + i;                dst = Xb   + i; }
    else if (i < M8 + M1)    { src = Wq + (i - M8);         dst = Wcat + (i - M8); }
    else if (i < M8 + 2*M1)  { src = Wk + (i - M8 - M1);    dst = Wcat + (i - M8); }
    else if (i < M8 + 3*M1)  { src = Wv + (i - M8 - 2*M1);  dst = Wcat + (i - M8); }
    else                     { src = Wo + (i - M8 - 3*M1);  dst = Wob  + (i - M8 - 3*M1); }
#pragma unroll
    for (int j = 0; j < 2; ++j) {
        float4 a = ((const float4*)src)[2 * j];
        float4 b = ((const float4*)src)[2 * j + 1];
        uint4 o;
        o.x = f2bf1(a.x) | (f2bf1(a.y) << 16);
        o.y = f2bf1(a.z) | (f2bf1(a.w) << 16);
        o.z = f2bf1(b.x) | (f2bf1(b.y) << 16);
        o.w = f2bf1(b.z) | (f2bf1(b.w) << 16);
        ((uint4*)dst)[j] = o;
    }
}

// ---------------------------------------------------------------------------
// Kernel 1: fused QKV GEMM (m97 structure). C[8192][3072] = Xb @ Wcat^T.
// q/k layout: [bh][g][dp'] with dp' = 2*dh + (s&1) -> packed u32 epilogue.
// v_t layout: [bh][dp][g-sigma] (PV key-permutation baked in).
// ---------------------------------------------------------------------------
__global__ __launch_bounds__(256) void qkv_gemm3(
    const u16* __restrict__ Xb, const u16* __restrict__ Wcat,
    const float* __restrict__ b0, const float* __restrict__ b1,
    const float* __restrict__ b2,
    u16* __restrict__ q_att, u16* __restrict__ k_att, u16* __restrict__ v_t)
{
    const int nb = blockIdx.x, mb = blockIdx.y;
    const int mat = nb >> 3;

    __shared__ __align__(16) u16 As[128 * 32];
    __shared__ __align__(16) u16 Bs[128 * 32];

    const int t = threadIdx.x, wave = t >> 6, lane = t & 63;
    const int l15 = lane & 15, quad = lane >> 4;
    const int wm = (wave >> 1) * 64, wn = (wave & 1) * 64;
    const int lrow = lane >> 2, lcb = (lane & 3) * 8;

    const u16* Ab = Xb   + (size_t)(mb * 128) * 1024;
    const u16* Bb = Wcat + (size_t)(nb * 128) * 1024;

    f32x4 acc[4][4] = {};

    for (int k0 = 0; k0 < 1024; k0 += 32) {
        __syncthreads();
#pragma unroll
        for (int j = 0; j < 2; ++j) {
            int chunk = wave * 2 + j;
            gld16(As + chunk * 512, Ab + (size_t)(chunk * 16 + lrow) * 1024 + k0 + lcb);
            gld16(Bs + chunk * 512, Bb + (size_t)(chunk * 16 + lrow) * 1024 + k0 + lcb);
        }
        __syncthreads();

        short8 af[4], bf[4];
#pragma unroll
        for (int mt = 0; mt < 4; ++mt)
            af[mt] = *(const short8*)(As + (wm + mt * 16 + l15) * 32 + quad * 8);
#pragma unroll
        for (int nt = 0; nt < 4; ++nt)
            bf[nt] = *(const short8*)(Bs + (wn + nt * 16 + l15) * 32 + quad * 8);
#pragma unroll
        for (int mt = 0; mt < 4; ++mt)
#pragma unroll
            for (int nt = 0; nt < 4; ++nt)
                acc[mt][nt] = MFMA16(af[mt], bf[nt], acc[mt][nt]);
    }

    const float* bias = (mat == 0) ? b0 : (mat == 1) ? b1 : b2;
    const float scl = (mat == 0) ? 0.125f : 1.0f;
#pragma unroll
    for (int nt = 0; nt < 4; ++nt) {
        int colm = (nb & 7) * 128 + wn + nt * 16 + l15;   // feature = h*64+dh
        float bv = bias[colm];
        int h = colm >> 6, dh = colm & 63;
#pragma unroll
        for (int mt = 0; mt < 4; ++mt) {
            int row0 = mb * 128 + wm + mt * 16 + quad * 4;
            int b = row0 >> 11, s0 = row0 & 2047;
            int bh = b * 16 + h, g0 = s0 >> 1;                // even
            float v0 = (acc[mt][nt][0] + bv) * scl, v1 = (acc[mt][nt][1] + bv) * scl;
            float v2 = (acc[mt][nt][2] + bv) * scl, v3 = (acc[mt][nt][3] + bv) * scl;
            if (mat == 2) {
                // keys (g0,g0+1): dp=dh from rows r0,r2; dp=dh+64 from r1,r3
                u32 w0 = f2bf1(v0) | (f2bf1(v2) << 16);
                u32 w1 = f2bf1(v1) | (f2bf1(v3) << 16);
                int j6 = g0 & 63;
                int gp = (g0 & ~63) + (j6 & 32) + ((j6 >> 2) & 3) * 8
                       + ((j6 >> 4) & 1) * 4 + (j6 & 3);      // sigma-permuted
                *(u32*)(v_t + ((size_t)(bh * 128 + dh) * 1024 + gp)) = w0;
                *(u32*)(v_t + ((size_t)(bh * 128 + dh + 64) * 1024 + gp)) = w1;
            } else {
                // dp' = 2*dh + (s&1): (r0,r1)->g0, (r2,r3)->g0+1, adjacent u16
                u16* dst = (mat == 0) ? q_att : k_att;
                u32 w0 = f2bf1(v0) | (f2bf1(v1) << 16);
                u32 w1 = f2bf1(v2) | (f2bf1(v3) << 16);
                size_t base = ((size_t)bh * 1024 + g0) * 128 + 2 * dh;
                *(u32*)(dst + base) = w0;
                *(u32*)(dst + base + 128) = w1;
            }
        }
    }
}

// ---------------------------------------------------------------------------
// Kernel 2: flash attention, transposed-S, global_load_lds staging with
// XOR-swizzled LDS. grid (16,64), 256 thr. (unchanged from R6 — the dp'
// permutation in q/k needs no change here: Q,K both read linearly.)
// ---------------------------------------------------------------------------
__global__ __launch_bounds__(256) void attn4(
    const u16* __restrict__ q_att, const u16* __restrict__ k_att,
    const u16* __restrict__ v_t, u16* __restrict__ ctx)
{
    const int bh = blockIdx.y, qb = blockIdx.x;
    const u16* Q = q_att + (size_t)bh * 131072;
    const u16* K = k_att + (size_t)bh * 131072;
    const u16* V = v_t  + (size_t)bh * 131072;     // [d'=128][g-sigma-permuted]

    __shared__ __align__(16) u16 Ks[64 * 128];     // 16KB
    __shared__ __align__(16) u16 Vs[128 * 64];     // 16KB

    const int t = threadIdx.x, wave = t >> 6, lane = t & 63;
    const int l15 = lane & 15, quad = lane >> 4;
    const int q_row = qb * 64 + wave * 16 + l15;

    // staging source offsets (u16 units), 4 K-chunks + 4 V-chunks per wave
    int offK[4], offV[4];
#pragma unroll
    for (int j = 0; j < 4; ++j) {
        int ck = wave * 4 + j;
        int rowK = ck * 4 + (lane >> 4);                       // 0..63
        offK[j] = rowK * 128 + (((lane & 15) ^ (rowK & 15)) * 8);
        int rowV = ck * 8 + (lane >> 3);                       // d' 0..127
        offV[j] = rowV * 1024 + (((lane & 7) ^ ((lane >> 3) & 7)) * 8);
    }

    // Q^T B-frags: n=l15=q, k over 4 blocks of 32 (dp'-order, matches K)
    short8 bq[4];
#pragma unroll
    for (int kb = 0; kb < 4; ++kb)
        bq[kb] = *(const short8*)(Q + (size_t)q_row * 128 + kb * 32 + quad * 8);

    f32x4 accO[8] = {};
    float m_i = -1e30f, l_i = 0.0f;

    for (int kt = 0; kt < 16; ++kt) {
        const u16* Kt = K + (size_t)kt * 8192;
        const u16* Vt = V + (size_t)kt * 64;
        __syncthreads();                            // prev tile's LDS reads done
#pragma unroll
        for (int j = 0; j < 4; ++j) {
            gld16(Ks + (wave * 4 + j) * 512, Kt + offK[j]);
            gld16(Vs + (wave * 4 + j) * 512, Vt + offV[j]);
        }
        __syncthreads();                            // drains vmcnt incl. lds-DMA

        // S^T: accS[kf] = K[16 keys] x Q^T  (Ks xor-swizzled reads)
        f32x4 accS[4] = {};
#pragma unroll
        for (int kf = 0; kf < 4; ++kf)
#pragma unroll
            for (int kb = 0; kb < 4; ++kb) {
                short8 ak = *(const short8*)(Ks + (kf * 16 + l15) * 128
                                             + (((kb * 4 + quad) ^ l15) * 8));
                accS[kf] = MFMA16(ak, bq[kb], accS[kf]);
            }

        // per-lane softmax over 64 keys
        float mloc = -1e30f;
#pragma unroll
        for (int kf = 0; kf < 4; ++kf)
            mloc = fmaxf(mloc, fmaxf(fmaxf(accS[kf][0], accS[kf][1]),
                                     fmaxf(accS[kf][2], accS[kf][3])));
        mloc = fmaxf(mloc, __shfl_xor(mloc, 16));
        mloc = fmaxf(mloc, __shfl_xor(mloc, 32));
        float mn = fmaxf(m_i, mloc);
        float alpha = __expf(m_i - mn);
        m_i = mn;

        float lsum = 0.0f;
        u32 pb[8];
#pragma unroll
        for (int kf = 0; kf < 4; ++kf) {
            float p0 = __expf(accS[kf][0] - mn);
            float p1 = __expf(accS[kf][1] - mn);
            float p2 = __expf(accS[kf][2] - mn);
            float p3 = __expf(accS[kf][3] - mn);
            lsum += (p0 + p1) + (p2 + p3);
            pb[kf * 2]     = f2bf1(p0) | (f2bf1(p1) << 16);
            pb[kf * 2 + 1] = f2bf1(p2) | (f2bf1(p3) << 16);
        }
        lsum += __shfl_xor(lsum, 16);
        lsum += __shfl_xor(lsum, 32);
        l_i = l_i * alpha + lsum;

#pragma unroll
        for (int f = 0; f < 8; ++f) {
            accO[f][0] *= alpha; accO[f][1] *= alpha;
            accO[f][2] *= alpha; accO[f][3] *= alpha;
        }

        // PV: O^T += V^T @ P^T (sigma baked into v_t; Vs xor-swizzled reads)
        S8 bp0, bp1;
        bp0.u[0] = pb[0]; bp0.u[1] = pb[1]; bp0.u[2] = pb[2]; bp0.u[3] = pb[3];
        bp1.u[0] = pb[4]; bp1.u[1] = pb[5]; bp1.u[2] = pb[6]; bp1.u[3] = pb[7];
        const int l7 = l15 & 7;
#pragma unroll
        for (int df = 0; df < 8; ++df) {
            const u16* vrow = Vs + (df * 16 + l15) * 64;
            short8 av0 = *(const short8*)(vrow + ((quad ^ l7) * 8));
            short8 av1 = *(const short8*)(vrow + (((quad + 4) ^ l7) * 8));
            accO[df] = MFMA16(av0, bp0.s, accO[df]);
            accO[df] = MFMA16(av1, bp1.s, accO[df]);
        }
    }

    // epilogue: O^T/l -> ctx[b][sp=2q+(h>>3)][(h&7)*128 + d'], 8B stores
    const int h = bh & 15, b = bh >> 4;
    float inv = 1.0f / l_i;
    size_t base = ((size_t)(b * 2048 + 2 * q_row + (h >> 3))) * 1024 + (h & 7) * 128;
#pragma unroll
    for (int df = 0; df < 8; ++df) {
        int dp = df * 16 + quad * 4;
        uint2 w;
        w.x = f2bf1(accO[df][0] * inv) | (f2bf1(accO[df][1] * inv) << 16);
        w.y = f2bf1(accO[df][2] * inv) | (f2bf1(accO[df][3] * inv) << 16);
        *(uint2*)(ctx + base + dp) = w;
    }
}

// ---------------------------------------------------------------------------
// Kernel 3: out = ctx(bf16) @ Wob^T + bo -> fp32. 128x128 m97 tile, grid (8,64).
// (R3's 64x128 split halved MFMA-per-barrier; reverted per m103 tile-space.)
// ---------------------------------------------------------------------------
__global__ __launch_bounds__(256) void out_gemm4(
    const u16* __restrict__ ctx, const u16* __restrict__ Wob,
    const float* __restrict__ bo, float* __restrict__ out)
{
    const int nb = blockIdx.x, mb = blockIdx.y;
    __shared__ __align__(16) u16 As[128 * 32];
    __shared__ __align__(16) u16 Bs[128 * 32];
    const int t = threadIdx.x, wave = t >> 6, lane = t & 63;
    const int l15 = lane & 15, quad = lane >> 4;
    const int wm = (wave >> 1) * 64, wn = (wave & 1) * 64;
    const int lrow = lane >> 2, lcb = (lane & 3) * 8;

    const u16* Ab = ctx + (size_t)(mb * 128) * 1024;
    const u16* Bb = Wob + (size_t)(nb * 128) * 1024;

    f32x4 acc[4][4] = {};

    for (int k0 = 0; k0 < 1024; k0 += 32) {
        __syncthreads();
#pragma unroll
        for (int j = 0; j < 2; ++j) {
            int chunk = wave * 2 + j;
            gld16(As + chunk * 512, Ab + (size_t)(chunk * 16 + lrow) * 1024 + k0 + lcb);
            gld16(Bs + chunk * 512, Bb + (size_t)(chunk * 16 + lrow) * 1024 + k0 + lcb);
        }
        __syncthreads();

        short8 af[4], bf[4];
#pragma unroll
        for (int mt = 0; mt < 4; ++mt)
            af[mt] = *(const short8*)(As + (wm + mt * 16 + l15) * 32 + quad * 8);
#pragma unroll
        for (int nt = 0; nt < 4; ++nt)
            bf[nt] = *(const short8*)(Bs + (wn + nt * 16 + l15) * 32 + quad * 8);
#pragma unroll
        for (int mt = 0; mt < 4; ++mt)
#pragma unroll
            for (int nt = 0; nt < 4; ++nt)
                acc[mt][nt] = MFMA16(af[mt], bf[nt], acc[mt][nt]);
    }

#pragma unroll
    for (int nt = 0; nt < 4; ++nt) {
        int col = nb * 128 + wn + nt * 16 + l15;
        float bv = bo[col];
#pragma unroll
        for (int mt = 0; mt < 4; ++mt)
#pragma unroll
            for (int r = 0; r < 4; ++r) {
                int row = mb * 128 + wm + mt * 16 + quad * 4 + r;
                out[(size_t)row * 1024 + col] = acc[mt][nt][r] + bv;
            }
    }
}

// ---------------------------------------------------------------------------
extern "C" void kernel_launch(void* const* d_in, const int* in_sizes, int n_in,
                              void* d_out, int out_size, void* d_ws, size_t ws_size,
                              hipStream_t stream)
{
    const float* X  = (const float*)d_in[0];
    const float* Wq = (const float*)d_in[1];
    const float* bq = (const float*)d_in[2];
    const float* Wk = (const float*)d_in[3];
    const float* bk = (const float*)d_in[4];
    const float* Wv = (const float*)d_in[5];
    const float* bv = (const float*)d_in[6];
    const float* Wo = (const float*)d_in[7];
    const float* bo = (const float*)d_in[8];

    const size_t M8 = 8388608;
    u16* q_att = (u16*)d_ws;
    u16* k_att = q_att + M8;
    u16* v_t   = k_att + M8;
    u16* Xb    = v_t   + M8;            // Xb dead after qkv -> ctx aliases it
    u16* ctx   = Xb;
    u16* Wcat  = Xb + M8;
    u16* Wob   = Wcat + 3 * 1048576;

    convert<<<dim3(3072), 256, 0, stream>>>(X, Wq, Wk, Wv, Wo, Xb, Wcat, Wob);
    qkv_gemm3<<<dim3(24, 64), 256, 0, stream>>>(Xb, Wcat, bq, bk, bv,
                                                q_att, k_att, v_t);
    attn4<<<dim3(16, 64), 256, 0, stream>>>(q_att, k_att, v_t, ctx);
    out_gemm4<<<dim3(8, 64), 256, 0, stream>>>(ctx, Wob, bo, (float*)d_out);
}